// Round 1
// baseline (2209.345 us; speedup 1.0000x reference)
//
#include <hip/hip_runtime.h>
#include <hip/hip_bf16.h>
#include <stdint.h>

#define H_DIM 2048
#define F_DIM 8192
#define N_EXP 8
#define T_TOK 4096
#define TILE  128
#define BK    32          // legacy k-step
#define BKP   40          // legacy padded LDS k-stride
#define BKF   64          // fast-path k-step (8x 16B granules per row)
#define MAX_TILES 72      // sum_e ceil(n_e/128) <= (8192 + 8*127)/128 < 72

typedef short bf16x8 __attribute__((ext_vector_type(8)));
typedef float f32x4  __attribute__((ext_vector_type(4)));
typedef unsigned short u16;
typedef unsigned int   u32;

__device__ __forceinline__ u16 f2bf(float f) {
    __hip_bfloat16 h = __float2bfloat16(f);   // RNE
    return *reinterpret_cast<u16*>(&h);
}
__device__ __forceinline__ u32 pack2(float a, float b) {
    return (u32)f2bf(a) | ((u32)f2bf(b) << 16);
}
__device__ __forceinline__ float gelu_tanh(float v) {
    float z = 0.7978845608028654f * (v + 0.044715f * v * v * v);
    float t = __builtin_amdgcn_exp2f(z * 2.8853900817779268f);  // e^(2z)
    float th = 1.f - 2.f * __builtin_amdgcn_rcpf(t + 1.f);
    return 0.5f * v * (1.f + th);
}

// async global->LDS, 16B per lane; LDS dest = wave-uniform base + lane*16
__device__ __forceinline__ void gload16(const void* g, void* l) {
    __builtin_amdgcn_global_load_lds(
        (const __attribute__((address_space(1))) void*)g,
        (__attribute__((address_space(3))) void*)l, 16, 0, 0);
}

// ---------------- router: logits, top-2, softmax, scatter to expert lists ----
__global__ void router_kernel(const float* __restrict__ x, const float* __restrict__ rw,
                              int* __restrict__ cnt, int* __restrict__ toks,
                              float* __restrict__ gates) {
    int wave = threadIdx.x >> 6;
    int lane = threadIdx.x & 63;
    int t = blockIdx.x * 4 + wave;
    const float* xp = x + (size_t)t * H_DIM;
    float acc[N_EXP];
#pragma unroll
    for (int e = 0; e < N_EXP; e++) acc[e] = 0.f;
    for (int j = 0; j < H_DIM / 64; j++) {
        int hh = j * 64 + lane;
        float xv = xp[hh];
        const float4* r4 = reinterpret_cast<const float4*>(rw + (size_t)hh * N_EXP);
        float4 r0 = r4[0], r1 = r4[1];
        acc[0] += xv * r0.x; acc[1] += xv * r0.y; acc[2] += xv * r0.z; acc[3] += xv * r0.w;
        acc[4] += xv * r1.x; acc[5] += xv * r1.y; acc[6] += xv * r1.z; acc[7] += xv * r1.w;
    }
#pragma unroll
    for (int off = 32; off >= 1; off >>= 1) {
#pragma unroll
        for (int e = 0; e < N_EXP; e++) acc[e] += __shfl_xor(acc[e], off, 64);
    }
    if (lane == 0) {
        int e0 = 0; float v0 = acc[0];
#pragma unroll
        for (int e = 1; e < N_EXP; e++) if (acc[e] > v0) { v0 = acc[e]; e0 = e; }
        int e1 = -1; float v1 = -3.0e38f;
#pragma unroll
        for (int e = 0; e < N_EXP; e++) if (e != e0 && acc[e] > v1) { v1 = acc[e]; e1 = e; }
        float p = __builtin_amdgcn_exp2f((v1 - v0) * 1.4426950408889634f);
        float rden = __builtin_amdgcn_rcpf(1.f + p);
        float g0 = rden, g1 = p * rden;
        int p0 = atomicAdd(&cnt[e0], 1);
        toks[e0 * T_TOK + p0] = t; gates[e0 * T_TOK + p0] = g0;
        int p1 = atomicAdd(&cnt[e1], 1);
        toks[e1 * T_TOK + p1] = t; gates[e1 * T_TOK + p1] = g1;
    }
}

// ---------------- schedule: per-expert tile list ----------------------------
__global__ void sched_kernel(const int* __restrict__ cnt, int* __restrict__ sched,
                             int* __restrict__ total) {
    int tt = 0;
    for (int e = 0; e < N_EXP; e++) {
        int n = cnt[e];
        int nt = (n + TILE - 1) / TILE;
        for (int i = 0; i < nt; i++) {
            sched[2 * tt] = e;
            sched[2 * tt + 1] = e * T_TOK + i * TILE;
            tt++;
        }
    }
    *total = tt;
}

// ---------------- fast path: one-time converts ------------------------------
// x [T][H] fp32 -> xbf [T][H] bf16 (linear)
__global__ void convx_kernel(const float* __restrict__ x, u16* __restrict__ xbf) {
    int idx = (blockIdx.x * 256 + threadIdx.x) * 8;
    const float4* p = reinterpret_cast<const float4*>(x + idx);
    float4 a0 = p[0], a1 = p[1];
    *reinterpret_cast<uint4*>(xbf + idx) =
        make_uint4(pack2(a0.x, a0.y), pack2(a0.z, a0.w),
                   pack2(a1.x, a1.y), pack2(a1.z, a1.w));
}

// w [E][K][N] fp32 -> wt [E][N][K] bf16 (transpose via LDS 64x64 tiles)
// grid: (4096, 2, E); y=0 -> w1 (K=H,N=F), y=1 -> w2 (K=F,N=H)
__global__ void convw_kernel(const float* __restrict__ w1, const float* __restrict__ w2,
                             u16* __restrict__ w1t, u16* __restrict__ w2t) {
    __shared__ u16 tl[64][72];   // 144B rows: 16B-aligned, bank-rotating
    int e = blockIdx.z;
    const float* src; u16* dst; int K, N;
    if (blockIdx.y == 0) {
        src = w1 + (size_t)e * H_DIM * F_DIM; dst = w1t + (size_t)e * H_DIM * F_DIM;
        K = H_DIM; N = F_DIM;
    } else {
        src = w2 + (size_t)e * H_DIM * F_DIM; dst = w2t + (size_t)e * H_DIM * F_DIM;
        K = F_DIM; N = H_DIM;
    }
    int ntn = N >> 6;
    int kt = blockIdx.x / ntn, nt = blockIdx.x % ntn;
    int k0 = kt * 64, n0 = nt * 64;
    int tid = threadIdx.x;
    int r = tid >> 2, c4 = tid & 3;
    // read 16 fp32 at (k0+r, n0+c4*16), convert, store to LDS tile
    const float4* p = reinterpret_cast<const float4*>(src + (size_t)(k0 + r) * N + n0 + c4 * 16);
    float4 a0 = p[0], a1 = p[1], a2 = p[2], a3 = p[3];
    *reinterpret_cast<uint4*>(&tl[r][c4 * 16]) =
        make_uint4(pack2(a0.x, a0.y), pack2(a0.z, a0.w), pack2(a1.x, a1.y), pack2(a1.z, a1.w));
    *reinterpret_cast<uint4*>(&tl[r][c4 * 16 + 8]) =
        make_uint4(pack2(a2.x, a2.y), pack2(a2.z, a2.w), pack2(a3.x, a3.y), pack2(a3.z, a3.w));
    __syncthreads();
    // write transposed: out row n0+r, cols k0+c4*16..+15
    u32 w[8];
#pragma unroll
    for (int i = 0; i < 8; i++)
        w[i] = (u32)tl[c4 * 16 + 2 * i][r] | ((u32)tl[c4 * 16 + 2 * i + 1][r] << 16);
    uint4* q = reinterpret_cast<uint4*>(dst + (size_t)(n0 + r) * K + k0 + c4 * 16);
    q[0] = make_uint4(w[0], w[1], w[2], w[3]);
    q[1] = make_uint4(w[4], w[5], w[6], w[7]);
}

// ---------------- fast GEMM1: h = gelu(gather(xbf) @ w1t^T), bf16 out -------
// m97 structure: global_load_lds width-16 staging, BK=64, source-side XOR swizzle.
__global__ __launch_bounds__(256, 3)
void gemm1f_kernel(const u16* __restrict__ xbf, const u16* __restrict__ w1t,
                   const int* __restrict__ toks, const int* __restrict__ sched,
                   const int* __restrict__ total, u16* __restrict__ hbuf,
                   int tileBase) {
    __shared__ u16 As[TILE * BKF];   // [128][64] linear (global_load_lds dest)
    __shared__ u16 Bs[TILE * BKF];
    __shared__ int tokL[TILE];
    int tile = tileBase + blockIdx.x;
    if (tile >= *total) return;
    int e = sched[2 * tile];
    int slot0 = sched[2 * tile + 1];
    int tid = threadIdx.x;
    if (tid < TILE) tokL[tid] = toks[slot0 + tid];
    __syncthreads();

    int n0 = blockIdx.y * TILE;
    const u16* w1e = w1t + (size_t)e * H_DIM * F_DIM;   // [N=F][K=H]
    int lane = tid & 63, wv = tid >> 6;
    int wm = (wv & 1) * 64, wn = (wv >> 1) * 64;
    int fr = lane & 15, qd = lane >> 4;

    // staging: granule g = i*256+tid -> row g>>3, slot g&7; source quarter = slot ^ (row&7)
    int gs = tid & 7;
    const u16* asrc[4]; const u16* bsrc[4];
#pragma unroll
    for (int i = 0; i < 4; i++) {
        int rr = i * 32 + (tid >> 3);
        asrc[i] = xbf + (size_t)tokL[rr] * H_DIM + ((gs ^ (rr & 7)) * 8);
        bsrc[i] = w1e + (size_t)(n0 + rr) * H_DIM + ((gs ^ (rr & 7)) * 8);
    }
    char* aB = (char*)As + wv * 1024;
    char* bB = (char*)Bs + wv * 1024;

    f32x4 acc[4][4];
#pragma unroll
    for (int i = 0; i < 4; i++)
#pragma unroll
        for (int j = 0; j < 4; j++) acc[i][j] = (f32x4)0.f;

    for (int k0 = 0; k0 < H_DIM; k0 += BKF) {
#pragma unroll
        for (int i = 0; i < 4; i++) gload16(asrc[i] + k0, aB + i * 4096);
#pragma unroll
        for (int i = 0; i < 4; i++) gload16(bsrc[i] + k0, bB + i * 4096);
        __syncthreads();   // compiler drains vmcnt before s_barrier
#pragma unroll
        for (int s = 0; s < 2; s++) {
            bf16x8 aF[4], bF[4];
#pragma unroll
            for (int i = 0; i < 4; i++) {
                int row = wm + i * 16 + fr;
                aF[i] = *reinterpret_cast<const bf16x8*>(
                    &As[row * BKF + (((s * 4 + qd) ^ (row & 7)) * 8)]);
            }
#pragma unroll
            for (int j = 0; j < 4; j++) {
                int row = wn + j * 16 + fr;
                bF[j] = *reinterpret_cast<const bf16x8*>(
                    &Bs[row * BKF + (((s * 4 + qd) ^ (row & 7)) * 8)]);
            }
#pragma unroll
            for (int i = 0; i < 4; i++)
#pragma unroll
                for (int j = 0; j < 4; j++)
                    acc[i][j] = __builtin_amdgcn_mfma_f32_16x16x32_bf16(aF[i], bF[j], acc[i][j], 0, 0, 0);
        }
        __syncthreads();
    }

    size_t hb = (size_t)blockIdx.x * TILE * F_DIM;
#pragma unroll
    for (int i = 0; i < 4; i++) {
#pragma unroll
        for (int j = 0; j < 4; j++) {
#pragma unroll
            for (int r = 0; r < 4; r++) {
                int row = wm + i * 16 + qd * 4 + r;
                int col = n0 + wn + j * 16 + fr;
                hbuf[hb + (size_t)row * F_DIM + col] = f2bf(gelu_tanh(acc[i][j][r]));
            }
        }
    }
}

// ---------------- fast GEMM2: y[tok] += gate * (h @ w2t^T) ------------------
__global__ __launch_bounds__(256, 3)
void gemm2f_kernel(const u16* __restrict__ hbuf, const u16* __restrict__ w2t,
                   const int* __restrict__ toks, const float* __restrict__ gatesArr,
                   const int* __restrict__ sched, const int* __restrict__ total,
                   float* __restrict__ y, int tileBase) {
    __shared__ u16 As[TILE * BKF];
    __shared__ u16 Bs[TILE * BKF];
    __shared__ int tokL[TILE];
    __shared__ float gateL[TILE];
    int tile = tileBase + blockIdx.x;
    if (tile >= *total) return;
    int e = sched[2 * tile];
    int slot0 = sched[2 * tile + 1];
    int tid = threadIdx.x;
    if (tid < TILE) { tokL[tid] = toks[slot0 + tid]; gateL[tid] = gatesArr[slot0 + tid]; }
    __syncthreads();

    int n0 = blockIdx.y * TILE;
    const u16* w2e = w2t + (size_t)e * H_DIM * F_DIM;   // [N=H][K=F]
    const u16* hbase = hbuf + (size_t)blockIdx.x * TILE * F_DIM;
    int lane = tid & 63, wv = tid >> 6;
    int wm = (wv & 1) * 64, wn = (wv >> 1) * 64;
    int fr = lane & 15, qd = lane >> 4;

    int gs = tid & 7;
    const u16* asrc[4]; const u16* bsrc[4];
#pragma unroll
    for (int i = 0; i < 4; i++) {
        int rr = i * 32 + (tid >> 3);
        asrc[i] = hbase + (size_t)rr * F_DIM + ((gs ^ (rr & 7)) * 8);
        bsrc[i] = w2e + (size_t)(n0 + rr) * F_DIM + ((gs ^ (rr & 7)) * 8);
    }
    char* aB = (char*)As + wv * 1024;
    char* bB = (char*)Bs + wv * 1024;

    f32x4 acc[4][4];
#pragma unroll
    for (int i = 0; i < 4; i++)
#pragma unroll
        for (int j = 0; j < 4; j++) acc[i][j] = (f32x4)0.f;

    for (int k0 = 0; k0 < F_DIM; k0 += BKF) {
#pragma unroll
        for (int i = 0; i < 4; i++) gload16(asrc[i] + k0, aB + i * 4096);
#pragma unroll
        for (int i = 0; i < 4; i++) gload16(bsrc[i] + k0, bB + i * 4096);
        __syncthreads();
#pragma unroll
        for (int s = 0; s < 2; s++) {
            bf16x8 aF[4], bF[4];
#pragma unroll
            for (int i = 0; i < 4; i++) {
                int row = wm + i * 16 + fr;
                aF[i] = *reinterpret_cast<const bf16x8*>(
                    &As[row * BKF + (((s * 4 + qd) ^ (row & 7)) * 8)]);
            }
#pragma unroll
            for (int j = 0; j < 4; j++) {
                int row = wn + j * 16 + fr;
                bF[j] = *reinterpret_cast<const bf16x8*>(
                    &Bs[row * BKF + (((s * 4 + qd) ^ (row & 7)) * 8)]);
            }
#pragma unroll
            for (int i = 0; i < 4; i++)
#pragma unroll
                for (int j = 0; j < 4; j++)
                    acc[i][j] = __builtin_amdgcn_mfma_f32_16x16x32_bf16(aF[i], bF[j], acc[i][j], 0, 0, 0);
        }
        __syncthreads();
    }

#pragma unroll
    for (int i = 0; i < 4; i++) {
#pragma unroll
        for (int j = 0; j < 4; j++) {
#pragma unroll
            for (int r = 0; r < 4; r++) {
                int row = wm + i * 16 + qd * 4 + r;
                int col = n0 + wn + j * 16 + fr;
                float v = acc[i][j][r] * gateL[row];
                atomicAdd(&y[(size_t)tokL[row] * H_DIM + col], v);
            }
        }
    }
}

// ---------------- legacy path (fp32 in-loop convert) — unchanged fallback ---
__global__ void gemm1_kernel(const float* __restrict__ x, const float* __restrict__ w1,
                             const int* __restrict__ toks, const int* __restrict__ sched,
                             const int* __restrict__ total, u16* __restrict__ hbuf,
                             int tileBase) {
    __shared__ u16 As[TILE * BKP];
    __shared__ u16 Bs[TILE * BKP];
    __shared__ int tokL[TILE];
    int tile = tileBase + blockIdx.x;
    if (tile >= *total) return;
    int e = sched[2 * tile];
    int slot0 = sched[2 * tile + 1];
    int tid = threadIdx.x;
    if (tid < TILE) tokL[tid] = toks[slot0 + tid];
    __syncthreads();

    const float* w1e = w1 + (size_t)e * H_DIM * F_DIM;
    int n0 = blockIdx.y * TILE;

    int lane = tid & 63;
    int wv = tid >> 6;
    int wm = (wv & 1) * 64;
    int wn = (wv >> 1) * 64;
    int fr = lane & 15, qd = lane >> 4;

    int arow = tid >> 1, ahalf = tid & 1;
    const float* xrow = x + (size_t)tokL[arow] * H_DIM + ahalf * 16;
    u16* asp = &As[arow * BKP + ahalf * 16];
    int bk = tid & 31, bg = tid >> 5;

    f32x4 acc[4][4];
#pragma unroll
    for (int i = 0; i < 4; i++)
#pragma unroll
        for (int j = 0; j < 4; j++) acc[i][j] = (f32x4)0.f;

    for (int k0 = 0; k0 < H_DIM; k0 += BK) {
        {
            const float4* p = reinterpret_cast<const float4*>(xrow + k0);
            float4 a0 = p[0], a1 = p[1], a2 = p[2], a3 = p[3];
            uint4 q0 = make_uint4(pack2(a0.x, a0.y), pack2(a0.z, a0.w),
                                  pack2(a1.x, a1.y), pack2(a1.z, a1.w));
            uint4 q1 = make_uint4(pack2(a2.x, a2.y), pack2(a2.z, a2.w),
                                  pack2(a3.x, a3.y), pack2(a3.z, a3.w));
            *reinterpret_cast<uint4*>(asp) = q0;
            *reinterpret_cast<uint4*>(asp + 8) = q1;
        }
        {
            const float4* p = reinterpret_cast<const float4*>(
                w1e + (size_t)(k0 + bk) * F_DIM + n0 + bg * 16);
            float4 b0 = p[0], b1 = p[1], b2 = p[2], b3 = p[3];
            u16* bp = &Bs[(bg * 16) * BKP + bk];
            bp[0 * BKP]  = f2bf(b0.x); bp[1 * BKP]  = f2bf(b0.y);
            bp[2 * BKP]  = f2bf(b0.z); bp[3 * BKP]  = f2bf(b0.w);
            bp[4 * BKP]  = f2bf(b1.x); bp[5 * BKP]  = f2bf(b1.y);
            bp[6 * BKP]  = f2bf(b1.z); bp[7 * BKP]  = f2bf(b1.w);
            bp[8 * BKP]  = f2bf(b2.x); bp[9 * BKP]  = f2bf(b2.y);
            bp[10 * BKP] = f2bf(b2.z); bp[11 * BKP] = f2bf(b2.w);
            bp[12 * BKP] = f2bf(b3.x); bp[13 * BKP] = f2bf(b3.y);
            bp[14 * BKP] = f2bf(b3.z); bp[15 * BKP] = f2bf(b3.w);
        }
        __syncthreads();
        bf16x8 aF[4], bF[4];
#pragma unroll
        for (int i = 0; i < 4; i++)
            aF[i] = *reinterpret_cast<const bf16x8*>(&As[(wm + i * 16 + fr) * BKP + qd * 8]);
#pragma unroll
        for (int j = 0; j < 4; j++)
            bF[j] = *reinterpret_cast<const bf16x8*>(&Bs[(wn + j * 16 + fr) * BKP + qd * 8]);
#pragma unroll
        for (int i = 0; i < 4; i++)
#pragma unroll
            for (int j = 0; j < 4; j++)
                acc[i][j] = __builtin_amdgcn_mfma_f32_16x16x32_bf16(aF[i], bF[j], acc[i][j], 0, 0, 0);
        __syncthreads();
    }

    size_t hb = (size_t)blockIdx.x * TILE * F_DIM;
#pragma unroll
    for (int i = 0; i < 4; i++) {
#pragma unroll
        for (int j = 0; j < 4; j++) {
#pragma unroll
            for (int r = 0; r < 4; r++) {
                int row = wm + i * 16 + qd * 4 + r;
                int col = n0 + wn + j * 16 + fr;
                hbuf[hb + (size_t)row * F_DIM + col] = f2bf(gelu_tanh(acc[i][j][r]));
            }
        }
    }
}

__global__ void gemm2_kernel(const u16* __restrict__ hbuf, const float* __restrict__ w2,
                             const int* __restrict__ toks, const float* __restrict__ gatesArr,
                             const int* __restrict__ sched, const int* __restrict__ total,
                             float* __restrict__ y, int tileBase) {
    __shared__ u16 As[TILE * BKP];
    __shared__ u16 Bs[TILE * BKP];
    __shared__ int tokL[TILE];
    __shared__ float gateL[TILE];
    int tile = tileBase + blockIdx.x;
    if (tile >= *total) return;
    int e = sched[2 * tile];
    int slot0 = sched[2 * tile + 1];
    int tid = threadIdx.x;
    if (tid < TILE) { tokL[tid] = toks[slot0 + tid]; gateL[tid] = gatesArr[slot0 + tid]; }
    __syncthreads();

    const float* w2e = w2 + (size_t)e * F_DIM * H_DIM;
    int n0 = blockIdx.y * TILE;

    int lane = tid & 63;
    int wv = tid >> 6;
    int wm = (wv & 1) * 64;
    int wn = (wv >> 1) * 64;
    int fr = lane & 15, qd = lane >> 4;

    int arow = tid >> 1, ahalf = tid & 1;
    const u16* hrow = hbuf + ((size_t)blockIdx.x * TILE + arow) * F_DIM + ahalf * 16;
    u16* asp = &As[arow * BKP + ahalf * 16];
    int bk = tid & 31, bg = tid >> 5;

    f32x4 acc[4][4];
#pragma unroll
    for (int i = 0; i < 4; i++)
#pragma unroll
        for (int j = 0; j < 4; j++) acc[i][j] = (f32x4)0.f;

    for (int k0 = 0; k0 < F_DIM; k0 += BK) {
        {
            const uint4* p = reinterpret_cast<const uint4*>(hrow + k0);
            uint4 q0 = p[0], q1 = p[1];
            *reinterpret_cast<uint4*>(asp) = q0;
            *reinterpret_cast<uint4*>(asp + 8) = q1;
        }
        {
            const float4* p = reinterpret_cast<const float4*>(
                w2e + (size_t)(k0 + bk) * H_DIM + n0 + bg * 16);
            float4 b0 = p[0], b1 = p[1], b2 = p[2], b3 = p[3];
            u16* bp = &Bs[(bg * 16) * BKP + bk];
            bp[0 * BKP]  = f2bf(b0.x); bp[1 * BKP]  = f2bf(b0.y);
            bp[2 * BKP]  = f2bf(b0.z); bp[3 * BKP]  = f2bf(b0.w);
            bp[4 * BKP]  = f2bf(b1.x); bp[5 * BKP]  = f2bf(b1.y);
            bp[6 * BKP]  = f2bf(b1.z); bp[7 * BKP]  = f2bf(b1.w);
            bp[8 * BKP]  = f2bf(b2.x); bp[9 * BKP]  = f2bf(b2.y);
            bp[10 * BKP] = f2bf(b2.z); bp[11 * BKP] = f2bf(b2.w);
            bp[12 * BKP] = f2bf(b3.x); bp[13 * BKP] = f2bf(b3.y);
            bp[14 * BKP] = f2bf(b3.z); bp[15 * BKP] = f2bf(b3.w);
        }
        __syncthreads();
        bf16x8 aF[4], bF[4];
#pragma unroll
        for (int i = 0; i < 4; i++)
            aF[i] = *reinterpret_cast<const bf16x8*>(&As[(wm + i * 16 + fr) * BKP + qd * 8]);
#pragma unroll
        for (int j = 0; j < 4; j++)
            bF[j] = *reinterpret_cast<const bf16x8*>(&Bs[(wn + j * 16 + fr) * BKP + qd * 8]);
#pragma unroll
        for (int i = 0; i < 4; i++)
#pragma unroll
            for (int j = 0; j < 4; j++)
                acc[i][j] = __builtin_amdgcn_mfma_f32_16x16x32_bf16(aF[i], bF[j], acc[i][j], 0, 0, 0);
        __syncthreads();
    }

#pragma unroll
    for (int i = 0; i < 4; i++) {
#pragma unroll
        for (int j = 0; j < 4; j++) {
#pragma unroll
            for (int r = 0; r < 4; r++) {
                int row = wm + i * 16 + qd * 4 + r;
                int col = n0 + wn + j * 16 + fr;
                float v = acc[i][j][r] * gateL[row];
                atomicAdd(&y[(size_t)tokL[row] * H_DIM + col], v);
            }
        }
    }
}

// ---------------- host ------------------------------------------------------
extern "C" void kernel_launch(void* const* d_in, const int* in_sizes, int n_in,
                              void* d_out, int out_size, void* d_ws, size_t ws_size,
                              hipStream_t stream) {
    const float* x  = (const float*)d_in[0];
    const float* rw = (const float*)d_in[1];
    const float* w1 = (const float*)d_in[2];
    const float* w2 = (const float*)d_in[3];
    float* y = (float*)d_out;
    char* ws = (char*)d_ws;

    int*   cnt   = (int*)(ws);                     // 32 B
    int*   total = (int*)(ws + 64);                // 4 B
    int*   sched = (int*)(ws + 128);               // 576 B
    int*   toks  = (int*)(ws + 1024);              // 128 KiB
    float* gates = (float*)(ws + 1024 + 131072);   // 128 KiB, ends 263168

    const size_t XBF_OFF = 270336;                                        // 0x42000
    const size_t WT_SZ   = (size_t)N_EXP * H_DIM * F_DIM * 2;             // 256 MiB
    const size_t W1T_OFF = XBF_OFF + (size_t)T_TOK * H_DIM * 2;           // +16 MiB
    const size_t W2T_OFF = W1T_OFF + WT_SZ;
    const size_t FH_OFF  = W2T_OFF + WT_SZ;                               // ~530 MiB
    size_t tileBytes = (size_t)TILE * F_DIM * sizeof(u16);                // 2 MiB/tile

    hipMemsetAsync(ws, 0, XBF_OFF, stream);                       // counts/lists/sched
    hipMemsetAsync(d_out, 0, (size_t)out_size * sizeof(float), stream);

    router_kernel<<<T_TOK / 4, 256, 0, stream>>>(x, rw, cnt, toks, gates);
    sched_kernel<<<1, 1, 0, stream>>>(cnt, sched, total);

    if (ws_size >= FH_OFF + tileBytes) {
        // FAST path: pre-convert x + transposed bf16 weights, m97-style GEMMs
        u16* xbf  = (u16*)(ws + XBF_OFF);
        u16* w1t  = (u16*)(ws + W1T_OFF);
        u16* w2t  = (u16*)(ws + W2T_OFF);
        u16* hbuf = (u16*)(ws + FH_OFF);
        size_t havail = ws_size - FH_OFF;
        int tpc = (int)(havail / tileBytes);
        if (tpc > MAX_TILES) tpc = MAX_TILES;
        if (tpc < 1) tpc = 1;
        int nchunks = (MAX_TILES + tpc - 1) / tpc;

        convx_kernel<<<T_TOK * H_DIM / 2048, 256, 0, stream>>>(x, xbf);
        convw_kernel<<<dim3(4096, 2, N_EXP), 256, 0, stream>>>(w1, w2, w1t, w2t);
        for (int c = 0; c < nchunks; c++) {
            gemm1f_kernel<<<dim3(tpc, F_DIM / TILE), 256, 0, stream>>>(
                xbf, w1t, toks, sched, total, hbuf, c * tpc);
            gemm2f_kernel<<<dim3(tpc, H_DIM / TILE), 256, 0, stream>>>(
                hbuf, w2t, toks, gates, sched, total, y, c * tpc);
        }
    } else {
        // LEGACY fallback (previous verified kernel)
        u16* hbuf = (u16*)(ws + XBF_OFF);
        size_t havail = (ws_size > XBF_OFF) ? (ws_size - XBF_OFF) : 0;
        int tpc = (int)(havail / tileBytes);
        if (tpc > MAX_TILES) tpc = MAX_TILES;
        if (tpc < 1) tpc = 1;
        int nchunks = (MAX_TILES + tpc - 1) / tpc;
        for (int c = 0; c < nchunks; c++) {
            gemm1_kernel<<<dim3(tpc, F_DIM / TILE), 256, 0, stream>>>(
                x, w1, toks, sched, total, hbuf, c * tpc);
            gemm2_kernel<<<dim3(tpc, H_DIM / TILE), 256, 0, stream>>>(
                hbuf, w2, toks, gates, sched, total, y, c * tpc);
        }
    }
}